// Round 1
// baseline (100.013 us; speedup 1.0000x reference)
//
#include <hip/hip_runtime.h>
#include <hip/hip_bf16.h>

#define NN   768
#define INP  256
#define NH   4
#define FH   64
#define DOUT 256   // NH*FH

typedef _Float16 h2 __attribute__((ext_vector_type(2)));
typedef _Float16 h8 __attribute__((ext_vector_type(8)));
typedef float    f4 __attribute__((ext_vector_type(4)));

union HU { unsigned int u; h2 h; };

__device__ __forceinline__ float b2f(unsigned short u) {
    union { unsigned int i; float f; } v;
    v.i = ((unsigned int)u) << 16;
    return v.f;
}
__device__ __forceinline__ unsigned short f2b(float f) {
    union { float f; unsigned int i; } v; v.f = f;
    unsigned int lsb = (v.i >> 16) & 1;
    v.i += 0x7FFFu + lsb;
    return (unsigned short)(v.i >> 16);
}

// packed f16 add (v_pk_add_f16)
__device__ __forceinline__ unsigned int pkadd(unsigned int a, unsigned int b) {
    HU x, y, r; x.u = a; y.u = b; r.h = x.h + y.h; return r.u;
}
// acc += a2 . |s2|  (v_dot2_f32_f16 if available; abs via bit-and)
#if defined(__has_builtin)
#if __has_builtin(__builtin_amdgcn_fdot2)
#define HAVE_FDOT2 1
#endif
#endif
__device__ __forceinline__ float dot2abs(unsigned int a, unsigned int s, float acc) {
    HU x, y; x.u = a; y.u = s & 0x7FFF7FFFu;
#ifdef HAVE_FDOT2
    return __builtin_amdgcn_fdot2(x.h, y.h, acc, false);
#else
    return acc + (float)x.h.x * (float)y.h.x + (float)x.h.y * (float)y.h.y;
#endif
}

// dtype detect (measured: inputs are f32; keep the guard — cheap)
__device__ __forceinline__ int detect_bf16(const void* xin) {
    const unsigned int* xw = (const unsigned int*)xin;
    unsigned int u = xw[(threadIdx.x & 63) * 7];
    unsigned int e = (u >> 7) & 0xFFu;
    unsigned long long m = __ballot(e >= 124u && e <= 127u);
    return (__popcll(m) >= 32) ? 1 : 0;
}

// ---------------------------------------------------------------------------
// K1: Wx = x @ W^T.  192 blocks x 1024 threads (K-split x4 for occupancy:
// 0.75 -> ~4 waves/SIMD). Thread (o = tid&255, ks = tid>>8) computes the
// quarter-dot over k in [ks*64, ks*64+64) for 4 nodes; LDS reduce; threads
// 0..255 (waves 0..3, f = tid&63, h = tid>>6 — same shfl structure as the
// validated version) do the epilogue: Wxf16, BT, lin, apk, flag.
// ---------------------------------------------------------------------------
__global__ __launch_bounds__(1024) void wx_kernel(
    const void* __restrict__ xin, const void* __restrict__ Win,
    const void* __restrict__ ain,
    _Float16* __restrict__ Wxf, _Float16* __restrict__ BT,
    float* __restrict__ lin, unsigned int* __restrict__ apk,
    int* __restrict__ flagout)
{
    const int isbf = detect_bf16(xin);
    __shared__ float xs[4][INP];
    __shared__ float sa[64];
    __shared__ float part[3][4][256];   // ks=1..3 partials
    const int tid = threadIdx.x;
    const int r0  = blockIdx.x * 4;
    const int o   = tid & 255;
    const int ks  = tid >> 8;

    if (isbf) {
        const unsigned short* xp = (const unsigned short*)xin + r0 * INP;
        xs[tid >> 8][tid & 255] = b2f(xp[tid]);
    } else {
        const float* xp = (const float*)xin + r0 * INP;
        xs[tid >> 8][tid & 255] = xp[tid];
    }
    if (tid < 64)
        sa[tid] = isbf ? b2f(((const unsigned short*)ain)[tid])
                       : ((const float*)ain)[tid];
    __syncthreads();

    const int k0 = ks * 64;
    float acc0 = 0.f, acc1 = 0.f, acc2 = 0.f, acc3 = 0.f;
    if (isbf) {
        const unsigned short* wr = (const unsigned short*)Win + o * INP + k0;
        #pragma unroll 4
        for (int k = 0; k < 64; k += 4) {
            ushort4 u = *(const ushort4*)(wr + k);
            float4 w = make_float4(b2f(u.x), b2f(u.y), b2f(u.z), b2f(u.w));
            float4 x0 = *(const float4*)&xs[0][k0 + k];
            float4 x1 = *(const float4*)&xs[1][k0 + k];
            float4 x2 = *(const float4*)&xs[2][k0 + k];
            float4 x3 = *(const float4*)&xs[3][k0 + k];
            acc0 += x0.x * w.x + x0.y * w.y + x0.z * w.z + x0.w * w.w;
            acc1 += x1.x * w.x + x1.y * w.y + x1.z * w.z + x1.w * w.w;
            acc2 += x2.x * w.x + x2.y * w.y + x2.z * w.z + x2.w * w.w;
            acc3 += x3.x * w.x + x3.y * w.y + x3.z * w.z + x3.w * w.w;
        }
    } else {
        const float* wr = (const float*)Win + o * INP + k0;
        #pragma unroll 4
        for (int k = 0; k < 64; k += 4) {
            float4 w = *(const float4*)(wr + k);
            float4 x0 = *(const float4*)&xs[0][k0 + k];
            float4 x1 = *(const float4*)&xs[1][k0 + k];
            float4 x2 = *(const float4*)&xs[2][k0 + k];
            float4 x3 = *(const float4*)&xs[3][k0 + k];
            acc0 += x0.x * w.x + x0.y * w.y + x0.z * w.z + x0.w * w.w;
            acc1 += x1.x * w.x + x1.y * w.y + x1.z * w.z + x1.w * w.w;
            acc2 += x2.x * w.x + x2.y * w.y + x2.z * w.z + x2.w * w.w;
            acc3 += x3.x * w.x + x3.y * w.y + x3.z * w.z + x3.w * w.w;
        }
    }

    if (ks > 0) {
        part[ks - 1][0][o] = acc0;
        part[ks - 1][1][o] = acc1;
        part[ks - 1][2][o] = acc2;
        part[ks - 1][3][o] = acc3;
    }
    __syncthreads();
    if (ks == 0) {
        acc0 += part[0][0][o] + part[1][0][o] + part[2][0][o];
        acc1 += part[0][1][o] + part[1][1][o] + part[2][1][o];
        acc2 += part[0][2][o] + part[1][2][o] + part[2][2][o];
        acc3 += part[0][3][o] + part[1][3][o] + part[2][3][o];

        // row-major f16 Wx
        Wxf[(r0 + 0) * DOUT + o] = (_Float16)acc0;
        Wxf[(r0 + 1) * DOUT + o] = (_Float16)acc1;
        Wxf[(r0 + 2) * DOUT + o] = (_Float16)acc2;
        Wxf[(r0 + 3) * DOUT + o] = (_Float16)acc3;
        // transposed copy BT[o][node] for MFMA B-fragments (8B store, 4 nodes)
        {
            HU u0, u1;
            u0.h = h2{(_Float16)acc0, (_Float16)acc1};
            u1.h = h2{(_Float16)acc2, (_Float16)acc3};
            uint2 pv; pv.x = u0.u; pv.y = u1.u;
            *(uint2*)(BT + (size_t)o * NN + r0) = pv;
        }

        const int f = tid & 63;
        const int h = tid >> 6;
        if (blockIdx.x == 0) {
            if (tid == 0) *flagout = isbf;
            if (tid < 32) {
                HU p; p.h = h2{(_Float16)(0.4f * sa[2 * tid]),
                               (_Float16)(0.4f * sa[2 * tid + 1])};
                apk[tid] = p.u;
            }
        }

        const float af = 0.6f * sa[f];
        float v0 = af * acc0, v1 = af * acc1, v2 = af * acc2, v3 = af * acc3;
        #pragma unroll
        for (int d = 1; d < 64; d <<= 1) {
            v0 += __shfl_xor(v0, d);
            v1 += __shfl_xor(v1, d);
            v2 += __shfl_xor(v2, d);
            v3 += __shfl_xor(v3, d);
        }
        if (f == 0) {
            lin[(r0 + 0) * NH + h] = v0;
            lin[(r0 + 1) * NH + h] = v1;
            lin[(r0 + 2) * NH + h] = v2;
            lin[(r0 + 3) * NH + h] = v3;
        }
    }
}

// ---------------------------------------------------------------------------
// K2 (fused): e + softmax + AV-MFMA. Block = (4 i-rows, 1 head); grid 192x4
// = 768 blocks (vs 192 before: 0.75 -> 3 waves/SIMD). LDS 37.7 KB -> 4
// blocks/CU LDS-limit. MFMA fragment indexing identical to the validated
// 16-row version; P rows 4..15 zero-padded once so AV rows 4..15 are zeros
// (only quad0 lanes store).
// ---------------------------------------------------------------------------
#define RB 4     // i-rows per block (= #waves: softmax row-per-wave)
#define EP 772   // 768 + 4 f32 pad
#define KP 776   // 768 + 8 f16 pad
__global__ __launch_bounds__(256, 3) void gat_kernel(
    const _Float16* __restrict__ Wxf,
    const _Float16* __restrict__ BT,
    const float* __restrict__ lin,
    const unsigned int* __restrict__ apk,
    const int* __restrict__ adj,
    void* __restrict__ outv,
    const int* __restrict__ flag)
{
    __shared__ float E[RB][EP];                  // 12352 B
    __shared__ __align__(16) _Float16 P[16][KP]; // 24832 B (rows RB..15 zero)
    __shared__ float S[RB];
    __shared__ __align__(16) _Float16 WI[RB * FH]; // 512 B

    const int b    = blockIdx.x;
    const int h    = b & 3, it = b >> 2;
    const int i0   = it * RB;
    const int tid  = threadIdx.x;
    const int wv   = tid >> 6;
    const int lane = tid & 63;

    // zero P rows RB..15 (12 rows x KP f16 = 1164 uint4, contiguous)
    {
        uint4 z = {0u, 0u, 0u, 0u};
        uint4* pz = (uint4*)&P[RB][0];
        #pragma unroll 2
        for (int idx = tid; idx < ((16 - RB) * KP * 2) / 16; idx += 256)
            pz[idx] = z;
    }
    // stage the block's 4 wi rows (head slice) in LDS: 4 x 64 f16 = 128 words
    if (tid < RB * FH / 2) {
        ((unsigned int*)WI)[tid] =
            *(const unsigned int*)(Wxf + (size_t)(i0 + (tid >> 5)) * DOUT
                                   + h * FH + (tid & 31) * 2);
    }

    // 0.4*a packed, 8 x uint4 (wave-uniform)
    uint4 ap[8];
    #pragma unroll
    for (int c = 0; c < 8; ++c) ap[c] = *(const uint4*)(apk + c * 4);
    float lini[RB];
    #pragma unroll
    for (int r = 0; r < RB; ++r) lini[r] = lin[(i0 + r) * NH + h];
    __syncthreads();

    // ---- e-phase: j = s*256 + tid ----
    for (int s = 0; s < 3; ++s) {
        const int j = s * 256 + tid;
        uint4 wj[8];
        #pragma unroll
        for (int c = 0; c < 8; ++c)
            wj[c] = *(const uint4*)(Wxf + (size_t)j * DOUT + h * FH + c * 8);
        const float linj = lin[j * NH + h];

        #pragma unroll
        for (int r = 0; r < RB; ++r) {
            const int adjv = adj[(size_t)(i0 + r) * NN + j];
            float a0 = 0.f, a1 = 0.f, a2 = 0.f, a3 = 0.f;   // 4 chains for ILP
            #pragma unroll
            for (int c = 0; c < 8; ++c) {
                const uint4 wiv = *(const uint4*)&WI[r * FH + c * 8];
                a0 = dot2abs(ap[c].x, pkadd(wiv.x, wj[c].x), a0);
                a1 = dot2abs(ap[c].y, pkadd(wiv.y, wj[c].y), a1);
                a2 = dot2abs(ap[c].z, pkadd(wiv.z, wj[c].z), a2);
                a3 = dot2abs(ap[c].w, pkadd(wiv.w, wj[c].w), a3);
            }
            const float acc = (a0 + a1) + (a2 + a3);
            E[r][j] = adjv ? (acc + lini[r] + linj) : -__builtin_inff();
        }
    }
    __syncthreads();

    // ---- softmax: wave wv owns row wv ----
    {
        const int row = wv;
        float v[12];
        float m = -__builtin_inff();
        #pragma unroll
        for (int c = 0; c < 12; ++c) {
            v[c] = E[row][c * 64 + lane];
            m = fmaxf(m, v[c]);
        }
        #pragma unroll
        for (int d = 1; d < 64; d <<= 1) m = fmaxf(m, __shfl_xor(m, d));
        if (m == -__builtin_inff()) m = 0.f;   // all-masked row: exps -> 0, not NaN
        float sum = 0.f;
        #pragma unroll
        for (int c = 0; c < 12; ++c) {
            const float ev = __expf(v[c] - m);   // masked (-inf) -> 0
            sum += ev;
            P[row][c * 64 + lane] = (_Float16)ev;
        }
        #pragma unroll
        for (int d = 1; d < 64; d <<= 1) sum += __shfl_xor(sum, d);
        if (lane == 0) S[row] = fmaxf(sum, 1e-30f);
    }
    __syncthreads();

    // ---- MFMA AV: out[RBx64] = P[16x768] . B[768x64], rows >= RB are zero ----
    const int mrow = lane & 15;
    const int quad = lane >> 4;
    const int n0   = wv * 16;
    f4 acc = {0.f, 0.f, 0.f, 0.f};
    const _Float16* bbase = BT + ((size_t)(h * FH + n0 + mrow)) * NN + quad * 8;
    const _Float16* abase = &P[mrow][quad * 8];
    #pragma unroll 4
    for (int k0 = 0; k0 < NN; k0 += 32) {
        const h8 af = *(const h8*)(abase + k0);
        const h8 bf = *(const h8*)(bbase + k0);
        acc = __builtin_amdgcn_mfma_f32_16x16x32_f16(af, bf, acc, 0, 0, 0);
    }

    // ---- normalize + store (C layout: col=lane&15, row=quad*4+r; only
    //      quad==0 holds valid rows 0..3) ----
    const int isbf = *flag;
    if (quad == 0) {
        #pragma unroll
        for (int r = 0; r < RB; ++r) {
            const float val = acc[r] / S[r];
            const size_t oidx = (size_t)(i0 + r) * DOUT + h * FH + n0 + mrow;
            if (isbf) ((unsigned short*)outv)[oidx] = f2b(val);
            else      ((float*)outv)[oidx] = val;
        }
    }
}

extern "C" void kernel_launch(void* const* d_in, const int* in_sizes, int n_in,
                              void* d_out, int out_size, void* d_ws, size_t ws_size,
                              hipStream_t stream) {
    const void* px = d_in[0]; const void* padj = d_in[1];
    const void* pW = d_in[2]; const void* pa  = d_in[3];
    for (int t = 0; t < n_in; ++t) {
        switch (in_sizes[t]) {
            case NN * INP:   px   = d_in[t]; break;   // 196608
            case NN * NN:    padj = d_in[t]; break;   // 589824
            case DOUT * INP: pW   = d_in[t]; break;   // 65536
            case FH:         pa   = d_in[t]; break;   // 64
        }
    }

    char* ws = (char*)d_ws;
    int*          flag = (int*)ws;                         // [0,256)
    unsigned int* apk  = (unsigned int*)(ws + 256);        // 128 B
    float*        lin  = (float*)(ws + 1024);              // 12288 B -> ends 13312
    _Float16*     Wxf  = (_Float16*)(ws + 16384);          // 393216 B -> ends 409600
    _Float16*     BT   = (_Float16*)(ws + 409600);         // 393216 B -> ends 802816

    wx_kernel<<<NN / 4, 1024, 0, stream>>>(px, pW, pa, Wxf, BT, lin, apk, flag);
    gat_kernel<<<(NN / RB) * NH, 256, 0, stream>>>(Wxf, BT, lin, apk,
                                                   (const int*)padj, d_out, flag);
}